// Round 1
// baseline (515.818 us; speedup 1.0000x reference)
//
#include <hip/hip_runtime.h>
#include <hip/hip_bf16.h>

#define PW 64
#define NV 512
#define HW 256
#define COV 16
#define BATCH 2048
#define XROW (PW * NV + COV)   // 32784

typedef short s16x8 __attribute__((ext_vector_type(8)));
typedef float f32x4 __attribute__((ext_vector_type(4)));

__device__ __forceinline__ unsigned short f2bf(float f) {
    union { float f; unsigned int u; } v;
    v.f = f;
    unsigned int u = v.u;
    unsigned int r = (u + 0x7fffu + ((u >> 16) & 1u)) >> 16;   // RNE
    return (unsigned short)r;
}

__device__ __forceinline__ float bf2f(unsigned short h) {
    union { unsigned int u; float f; } v;
    v.u = ((unsigned int)h) << 16;
    return v.f;
}

// ---------------------------------------------------------------------------
// Transpose + fp32->bf16 convert:  in[p] is (R x C) row-major -> out[p] is
// (C x R) row-major (i.e. N-major, K-contiguous for the GEMM B operand).
// ---------------------------------------------------------------------------
__global__ __launch_bounds__(256)
void transpose_convert(const float* __restrict__ in, unsigned short* __restrict__ out,
                       int R, int C) {
    __shared__ float tile[32][33];
    const int p = blockIdx.z;
    const int c0 = blockIdx.x * 32;
    const int r0 = blockIdx.y * 32;
    const float* ip = in + (size_t)p * R * C;
    unsigned short* op = out + (size_t)p * R * C;
    const int tx = threadIdx.x;   // 0..31
    const int ty = threadIdx.y;   // 0..7
    #pragma unroll
    for (int j = 0; j < 32; j += 8)
        tile[ty + j][tx] = ip[(size_t)(r0 + ty + j) * C + c0 + tx];
    __syncthreads();
    #pragma unroll
    for (int j = 0; j < 32; j += 8)
        op[(size_t)(c0 + ty + j) * R + r0 + tx] = f2bf(tile[tx][ty + j]);
}

// ---------------------------------------------------------------------------
// Grouped GEMM with fused LeakyReLU:  C[p] = lrelu(A[p] @ B[p])
//   A: (2048 x K), fp32 (CONV_A=true, converted in staging) or bf16
//   BT: (256 x K) bf16, N-major (pre-transposed)
//   C: (2048 x 256) bf16
// 128x128 output tile, BK=64, 4 waves (2x2 of 64x64), 16x16x32 bf16 MFMA.
// ---------------------------------------------------------------------------
template<int K, bool CONV_A>
__global__ __launch_bounds__(256)
void gemm_lrelu(const void* __restrict__ Abase, const unsigned short* __restrict__ BT,
                unsigned short* __restrict__ Cout,
                int lda, long aPs, long bPs, long cPs) {
    __shared__ __align__(16) unsigned short As[128][72];   // +8 pad: keeps 16B align, 2-way max
    __shared__ __align__(16) unsigned short Bs[128][72];

    const int p   = blockIdx.z;
    const int bm0 = blockIdx.x * 128;
    const int bn0 = blockIdx.y * 128;
    const int t    = threadIdx.x;
    const int lane = t & 63;
    const int wave = t >> 6;
    const int wm = (wave >> 1) * 64;
    const int wn = (wave & 1) * 64;
    const int l15  = lane & 15;
    const int quad = lane >> 4;

    f32x4 acc[4][4] = {};

    const unsigned short* Bp = BT + (size_t)p * bPs;

    for (int k0 = 0; k0 < K; k0 += 64) {
        if (CONV_A) {
            const float* Ap = (const float*)Abase + (size_t)p * aPs;
            #pragma unroll
            for (int i = 0; i < 8; ++i) {
                int idx = t + i * 256;           // 0..2047
                int row = idx >> 4;              // 16 float4 per 64-wide row
                int c4  = (idx & 15) * 4;
                float4 v = *(const float4*)(Ap + (size_t)(bm0 + row) * lda + k0 + c4);
                ushort4 u;
                u.x = f2bf(v.x); u.y = f2bf(v.y); u.z = f2bf(v.z); u.w = f2bf(v.w);
                *(ushort4*)&As[row][c4] = u;
            }
        } else {
            const unsigned short* Ap = (const unsigned short*)Abase + (size_t)p * aPs;
            #pragma unroll
            for (int i = 0; i < 4; ++i) {
                int idx = t + i * 256;           // 0..1023
                int row = idx >> 3;              // 8 x 16B chunks per row
                int c8  = (idx & 7) * 8;
                *(s16x8*)&As[row][c8] = *(const s16x8*)(Ap + (size_t)(bm0 + row) * lda + k0 + c8);
            }
        }
        #pragma unroll
        for (int i = 0; i < 4; ++i) {
            int idx = t + i * 256;
            int row = idx >> 3;
            int c8  = (idx & 7) * 8;
            *(s16x8*)&Bs[row][c8] = *(const s16x8*)(Bp + (size_t)(bn0 + row) * K + k0 + c8);
        }
        __syncthreads();

        #pragma unroll
        for (int kk = 0; kk < 64; kk += 32) {
            s16x8 af[4], bfr[4];
            #pragma unroll
            for (int mi = 0; mi < 4; ++mi)
                af[mi] = *(const s16x8*)&As[wm + mi * 16 + l15][kk + quad * 8];
            #pragma unroll
            for (int ni = 0; ni < 4; ++ni)
                bfr[ni] = *(const s16x8*)&Bs[wn + ni * 16 + l15][kk + quad * 8];
            #pragma unroll
            for (int mi = 0; mi < 4; ++mi)
                #pragma unroll
                for (int ni = 0; ni < 4; ++ni)
                    acc[mi][ni] = __builtin_amdgcn_mfma_f32_16x16x32_bf16(
                        af[mi], bfr[ni], acc[mi][ni], 0, 0, 0);
        }
        __syncthreads();
    }

    // epilogue: LeakyReLU, convert, store (C/D layout: col=lane&15, row=quad*4+reg)
    unsigned short* Cp = Cout + (size_t)p * cPs;
    #pragma unroll
    for (int mi = 0; mi < 4; ++mi) {
        #pragma unroll
        for (int ni = 0; ni < 4; ++ni) {
            int col = bn0 + wn + ni * 16 + l15;
            #pragma unroll
            for (int r = 0; r < 4; ++r) {
                int row = bm0 + wm + mi * 16 + quad * 4 + r;
                float v = acc[mi][ni][r];
                v = v >= 0.f ? v : 0.2f * v;
                Cp[(size_t)row * HW + col] = f2bf(v);
            }
        }
    }
}

// ---------------------------------------------------------------------------
// Stage C: pvec[p][b] = lrelu( dot(H2[p][b][:], W3[p][:]) ).  One wave per b.
// ---------------------------------------------------------------------------
__global__ __launch_bounds__(256)
void pathdot(const unsigned short* __restrict__ H2, const float* __restrict__ W3,
             float* __restrict__ pvec) {
    const int p    = blockIdx.y;
    const int wave = threadIdx.x >> 6;
    const int lane = threadIdx.x & 63;
    const int b    = blockIdx.x * 4 + wave;
    const unsigned short* h = H2 + ((size_t)p * BATCH + b) * HW + lane * 4;
    const float* w = W3 + (size_t)p * HW + lane * 4;
    ushort4 hv = *(const ushort4*)h;
    float4  wv = *(const float4*)w;
    float s = bf2f(hv.x) * wv.x + bf2f(hv.y) * wv.y +
              bf2f(hv.z) * wv.z + bf2f(hv.w) * wv.w;
    #pragma unroll
    for (int off = 32; off; off >>= 1) s += __shfl_down(s, off);
    if (lane == 0) {
        float v = s >= 0.f ? s : 0.2f * s;
        pvec[(size_t)p * BATCH + b] = v;
    }
}

// ---------------------------------------------------------------------------
// Per-pathway sum / sumsq over the batch.
// ---------------------------------------------------------------------------
__global__ __launch_bounds__(256)
void stats1(const float* __restrict__ pvec, float* __restrict__ sums) {
    const int p = blockIdx.x;
    float s = 0.f, q = 0.f;
    for (int i = threadIdx.x; i < BATCH; i += 256) {
        float v = pvec[(size_t)p * BATCH + i];
        s += v; q += v * v;
    }
    #pragma unroll
    for (int off = 32; off; off >>= 1) {
        s += __shfl_down(s, off);
        q += __shfl_down(q, off);
    }
    __shared__ float ls[4], lq[4];
    const int wave = threadIdx.x >> 6, lane = threadIdx.x & 63;
    if (lane == 0) { ls[wave] = s; lq[wave] = q; }
    __syncthreads();
    if (threadIdx.x == 0) {
        sums[p]      = ls[0] + ls[1] + ls[2] + ls[3];
        sums[64 + p] = lq[0] + lq[1] + lq[2] + lq[3];
    }
}

// ---------------------------------------------------------------------------
// mean / invstd per pathway + closed-form global Frobenius norm:
// ||pn||^2 = sum_p B * (gamma^2 * var/(var+eps) + beta^2)   (sum of zhat == 0)
// stat layout: [0..63]=mean, [64..127]=invstd, [128]=1/norm
// ---------------------------------------------------------------------------
__global__ void stats2(const float* __restrict__ sums, const float* __restrict__ gamma,
                       const float* __restrict__ beta, float* __restrict__ stat) {
    const int p = threadIdx.x;   // 64 threads, one wave
    float S = sums[p], Q = sums[64 + p];
    float mean = S * (1.f / BATCH);
    float var  = Q * (1.f / BATCH) - mean * mean;
    float invstd = rsqrtf(var + 1e-5f);
    stat[p]      = mean;
    stat[64 + p] = invstd;
    float g = gamma[p], bt = beta[p];
    float contrib = (float)BATCH * (g * g * var / (var + 1e-5f) + bt * bt);
    #pragma unroll
    for (int off = 32; off; off >>= 1) contrib += __shfl_down(contrib, off);
    if (p == 0) stat[128] = rsqrtf(contrib);
}

// ---------------------------------------------------------------------------
// Final: batchnorm-apply, /norm, concat covariates, linear, sigmoid.
// ---------------------------------------------------------------------------
__global__ __launch_bounds__(256)
void final_k(const float* __restrict__ pvec, const float* __restrict__ stat,
             const float* __restrict__ gamma, const float* __restrict__ beta,
             const float* __restrict__ x, const float* __restrict__ fc_w,
             const float* __restrict__ fc_b, float* __restrict__ out) {
    const int b = blockIdx.x * 256 + threadIdx.x;
    const float rn = stat[128];
    float acc = fc_b[0];
    #pragma unroll
    for (int p = 0; p < PW; ++p) {
        float pn = (pvec[(size_t)p * BATCH + b] - stat[p]) * stat[64 + p] * gamma[p] + beta[p];
        acc += pn * rn * fc_w[p];
    }
    #pragma unroll
    for (int c = 0; c < COV; ++c)
        acc += x[(size_t)b * XROW + PW * NV + c] * fc_w[PW + c];
    out[b] = 1.f / (1.f + __expf(-acc));
}

// ---------------------------------------------------------------------------
extern "C" void kernel_launch(void* const* d_in, const int* in_sizes, int n_in,
                              void* d_out, int out_size, void* d_ws, size_t ws_size,
                              hipStream_t stream) {
    const float* x     = (const float*)d_in[0];
    const float* W1    = (const float*)d_in[1];
    const float* W2    = (const float*)d_in[2];
    const float* W3    = (const float*)d_in[3];
    const float* gamma = (const float*)d_in[4];
    const float* beta  = (const float*)d_in[5];
    const float* fc_w  = (const float*)d_in[6];
    const float* fc_b  = (const float*)d_in[7];
    float* out = (float*)d_out;

    char* ws = (char*)d_ws;
    size_t off = 0;
    unsigned short* W1T = (unsigned short*)(ws + off); off += (size_t)PW * NV * HW * 2;      // 16.78 MB
    unsigned short* W2T = (unsigned short*)(ws + off); off += (size_t)PW * HW * HW * 2;      //  8.39 MB
    unsigned short* H1  = (unsigned short*)(ws + off); off += (size_t)PW * BATCH * HW * 2;   // 67.1 MB
    unsigned short* H2  = (unsigned short*)(ws + off); off += (size_t)PW * BATCH * HW * 2;   // 67.1 MB
    float* pvec = (float*)(ws + off); off += (size_t)PW * BATCH * 4;                          // 0.5 MB
    float* sums = (float*)(ws + off); off += 256 * 4;
    float* stat = (float*)(ws + off); off += 256 * 4;

    // 1) weight transpose+convert to bf16 N-major
    transpose_convert<<<dim3(HW / 32, NV / 32, PW), dim3(32, 8), 0, stream>>>(W1, W1T, NV, HW);
    transpose_convert<<<dim3(HW / 32, HW / 32, PW), dim3(32, 8), 0, stream>>>(W2, W2T, HW, HW);

    // 2) H1 = lrelu(x_p @ W1_p)   (A fp32, converted in staging)
    gemm_lrelu<NV, true><<<dim3(BATCH / 128, HW / 128, PW), 256, 0, stream>>>(
        (const void*)x, W1T, H1, XROW, (long)NV, (long)HW * NV, (long)BATCH * HW);

    // 3) H2 = lrelu(H1_p @ W2_p)
    gemm_lrelu<HW, false><<<dim3(BATCH / 128, HW / 128, PW), 256, 0, stream>>>(
        (const void*)H1, W2T, H2, HW, (long)BATCH * HW, (long)HW * HW, (long)BATCH * HW);

    // 4) pvec = lrelu(H2 . W3)
    pathdot<<<dim3(BATCH / 4, PW), 256, 0, stream>>>(H2, W3, pvec);

    // 5) batch stats + norm
    stats1<<<PW, 256, 0, stream>>>(pvec, sums);
    stats2<<<1, 64, 0, stream>>>(sums, gamma, beta, stat);

    // 6) final head
    final_k<<<BATCH / 256, 256, 0, stream>>>(pvec, stat, gamma, beta, x, fc_w, fc_b, out);
}